// Round 2
// baseline (7405.859 us; speedup 1.0000x reference)
//
#include <hip/hip_runtime.h>

#define EPS 1e-5f

// ---------------------------------------------------------------------------
// fill output mask with -100
// ---------------------------------------------------------------------------
__global__ void fill_kernel(float* __restrict__ out, int n, float v) {
    int i = blockIdx.x * blockDim.x + threadIdx.x;
    if (i < n) out[i] = v;
}

__global__ void zero8_kernel(float* __restrict__ a) {
    if (threadIdx.x < 8) a[threadIdx.x] = 0.f;
}

// ---------------------------------------------------------------------------
// GroupNorm(1) reduction: sum & sumsq over the (c, h, w) crop -> accs[2*batch]
// ---------------------------------------------------------------------------
__global__ void gn_reduce_kernel(const float* __restrict__ in, long long inBatchStride,
                                 int inPitch, long long inPlane, int useOrig,
                                 int c, int shift, const int* __restrict__ bboxes,
                                 int batch0, float* __restrict__ accs)
{
    int batch = batch0 + blockIdx.z;
    const int* bb = bboxes + 4 * batch;
    int l = bb[0], t = bb[1], r = bb[2], btm = bb[3];
    int h = (btm - t) << shift;
    int w = (r   - l) << shift;
    int oy = useOrig ? t : 0;   // only used at stage 0 (shift==0)
    int ox = useOrig ? l : 0;
    int count = c * h * w;
    const float* base = in + (long long)blockIdx.z * inBatchStride;

    float s = 0.f, s2 = 0.f;
    int stride = gridDim.x * blockDim.x;
    for (int idx = blockIdx.x * blockDim.x + threadIdx.x; idx < count; idx += stride) {
        int xw   = idx % w;
        int rest = idx / w;
        int y    = rest % h;
        int ch   = rest / h;
        float v = base[(long long)ch * inPlane + (long long)(y + oy) * inPitch + (xw + ox)];
        s  += v;
        s2 += v * v;
    }
    // wave64 reduction
    for (int off = 32; off > 0; off >>= 1) {
        s  += __shfl_down(s, off);
        s2 += __shfl_down(s2, off);
    }
    if ((threadIdx.x & 63) == 0) {
        atomicAdd(&accs[2 * batch],     s);
        atomicAdd(&accs[2 * batch + 1], s2);
    }
}

// ---------------------------------------------------------------------------
// normalize (affine folded) + bicubic 2x (both axes, 16 taps) + add em crop
// writes bufB (c, 2h, 2w) with pitch outPitch
// ---------------------------------------------------------------------------
__global__ void normup_kernel(const float* __restrict__ in, long long inBatchStride,
                              int inPitch, long long inPlane, int useOrig,
                              const float* __restrict__ em, long long emBatchStride, int emPitch,
                              const float* __restrict__ gw, const float* __restrict__ gb,
                              const float* __restrict__ accs,
                              float* __restrict__ outB, long long outBatchStride, int outPitch,
                              int c, int shift, const int* __restrict__ bboxes,
                              int batch0, int tilesY)
{
    int batch = batch0 + blockIdx.z;
    const int* bb = bboxes + 4 * batch;
    int l = bb[0], t = bb[1], r = bb[2], btm = bb[3];
    int h = (btm - t) << shift;
    int w = (r   - l) << shift;
    int H2 = 2 * h, W2 = 2 * w;

    int ch = blockIdx.y / tilesY;
    int ty = blockIdx.y % tilesY;
    int y2 = ty * 16 + threadIdx.y;
    int x2 = blockIdx.x * 16 + threadIdx.x;
    if (y2 >= H2 || x2 >= W2) return;

    float count = (float)(c * h * w);
    float m  = accs[2 * batch] / count;
    float var = accs[2 * batch + 1] / count - m * m;
    float rs = rsqrtf(fmaxf(var, 0.f) + EPS);
    float alpha = rs * gw[ch];
    float beta  = gb[ch] - m * alpha;

    int oy = useOrig ? t : 0;
    int ox = useOrig ? l : 0;
    const float* base = in + (long long)blockIdx.z * inBatchStride + (long long)ch * inPlane;

    const float Wv[2][4] = {
        {-0.03515625f, 0.26171875f, 0.87890625f, -0.10546875f},   // even (W75)
        {-0.10546875f, 0.87890625f, 0.26171875f, -0.03515625f}};  // odd  (W25)

    int iy = y2 >> 1, py = y2 & 1;
    int ix = x2 >> 1, px = x2 & 1;
    int by = iy - 2 + py;
    int bx = ix - 2 + px;

    float acc = 0.f;
    #pragma unroll
    for (int a = 0; a < 4; a++) {
        int ry = by + a;
        ry = ry < 0 ? 0 : (ry > h - 1 ? h - 1 : ry);
        const float* rowp = base + (long long)(ry + oy) * inPitch + ox;
        float rsum = 0.f;
        #pragma unroll
        for (int q = 0; q < 4; q++) {
            int rx = bx + q;
            rx = rx < 0 ? 0 : (rx > w - 1 ? w - 1 : rx);
            rsum += Wv[px][q] * rowp[rx];
        }
        acc += Wv[py][a] * rsum;
    }

    float val = alpha * acc + beta;
    int S = 2 << shift;  // 2^(j+1)
    val += em[(long long)blockIdx.z * emBatchStride + (long long)ch * emPitch * emPitch
              + (long long)(t * S + y2) * emPitch + (l * S + x2)];

    outB[(long long)blockIdx.z * outBatchStride + (long long)ch * outPitch * outPitch
         + (long long)y2 * outPitch + x2] = val;
}

// ---------------------------------------------------------------------------
// conv3x3 (zero pad) + bias (+ silu), ALL CO output channels per block.
// Block = 16x16 spatial tile; acc[CO] in registers; input tile staged in LDS
// in chunks of CICH planes; weights are block-uniform -> scalar loads.
// ---------------------------------------------------------------------------
#define CICH 4

template<int CO>
__global__ void conv_mc_kernel(const float* __restrict__ inB, long long inBatchStride, int inPitch,
                               const float* __restrict__ wts, const float* __restrict__ bias,
                               int cin, int doSilu,
                               float* __restrict__ out, long long outBatchStride, int outPitch,
                               int toMask, int shift, const int* __restrict__ bboxes,
                               int batch0)
{
    int batch = batch0 + blockIdx.z;
    const int* bb = bboxes + 4 * batch;
    int l = bb[0], t = bb[1], r = bb[2], btm = bb[3];
    int h = (btm - t) << shift;
    int w = (r   - l) << shift;
    int H2 = 2 * h, W2 = 2 * w;

    int y0 = blockIdx.y * 16;
    int x0 = blockIdx.x * 16;
    if (y0 >= H2 || x0 >= W2) return;  // uniform over block

    int ly = threadIdx.y, lx = threadIdx.x;
    int oy2 = y0 + ly, ox2 = x0 + lx;
    bool act = (oy2 < H2) && (ox2 < W2);
    int tid = ly * 16 + lx;

    // padded row stride 20 to break bank-conflict strides
    __shared__ float tile[CICH][18][20];

    const float* base = inB + (long long)blockIdx.z * inBatchStride;
    long long plane = (long long)inPitch * inPitch;

    float acc[CO];
    #pragma unroll
    for (int o = 0; o < CO; o++) acc[o] = 0.f;

    long long ocStride = (long long)cin * 9;

    for (int ci0 = 0; ci0 < cin; ci0 += CICH) {
        // stage CICH input planes (18x18 halo tile each) into LDS
        for (int q = tid; q < CICH * 324; q += 256) {
            int p   = q / 324;
            int rem = q - p * 324;
            int yy  = rem / 18;
            int xx  = rem - yy * 18;
            int gy = y0 - 1 + yy, gx = x0 - 1 + xx;
            float v = (gy >= 0 && gy < H2 && gx >= 0 && gx < W2)
                          ? base[(long long)(ci0 + p) * plane + (long long)gy * inPitch + gx]
                          : 0.f;
            tile[p][yy][xx] = v;
        }
        __syncthreads();

        #pragma unroll
        for (int p = 0; p < CICH; p++) {
            int ci = ci0 + p;
            // 9 input values for this thread's output pixel
            float v00 = tile[p][ly    ][lx], v01 = tile[p][ly    ][lx + 1], v02 = tile[p][ly    ][lx + 2];
            float v10 = tile[p][ly + 1][lx], v11 = tile[p][ly + 1][lx + 1], v12 = tile[p][ly + 1][lx + 2];
            float v20 = tile[p][ly + 2][lx], v21 = tile[p][ly + 2][lx + 1], v22 = tile[p][ly + 2][lx + 2];

            const float* wbase = wts + (long long)ci * 9;
            #pragma unroll
            for (int o = 0; o < CO; o++) {
                const float* wp = wbase + (long long)o * ocStride;  // block-uniform -> s_load
                acc[o] += wp[0] * v00 + wp[1] * v01 + wp[2] * v02
                        + wp[3] * v10 + wp[4] * v11 + wp[5] * v12
                        + wp[6] * v20 + wp[7] * v21 + wp[8] * v22;
            }
        }
        __syncthreads();
    }

    if (!act) return;

    #pragma unroll
    for (int o = 0; o < CO; o++) {
        float v = acc[o] + bias[o];
        if (doSilu) v = v / (1.f + __expf(-v));
        if (toMask) {
            int S = 2 << shift;   // 16 at stage 3
            out[(long long)batch * 1024 * 1024 + (long long)(t * S + oy2) * 1024 + (l * S + ox2)] = v;
        } else {
            out[(long long)blockIdx.z * outBatchStride + (long long)o * outPitch * outPitch
                + (long long)oy2 * outPitch + ox2] = v;
        }
    }
}

// ---------------------------------------------------------------------------
static inline void launch_conv(int co, dim3 grid, const float* inB, long long inBS, int inPitch,
                               const float* wts, const float* bias, int cin, int doSilu,
                               float* out, long long outBS, int outPitch,
                               int toMask, int shift, const int* bboxes, int batch0,
                               hipStream_t stream)
{
    dim3 blk(16, 16);
    switch (co) {
        case 64: conv_mc_kernel<64><<<grid, blk, 0, stream>>>(inB, inBS, inPitch, wts, bias, cin, doSilu,
                                                              out, outBS, outPitch, toMask, shift, bboxes, batch0); break;
        case 16: conv_mc_kernel<16><<<grid, blk, 0, stream>>>(inB, inBS, inPitch, wts, bias, cin, doSilu,
                                                              out, outBS, outPitch, toMask, shift, bboxes, batch0); break;
        case 4:  conv_mc_kernel<4><<<grid, blk, 0, stream>>>(inB, inBS, inPitch, wts, bias, cin, doSilu,
                                                             out, outBS, outPitch, toMask, shift, bboxes, batch0); break;
        default: conv_mc_kernel<1><<<grid, blk, 0, stream>>>(inB, inBS, inPitch, wts, bias, cin, doSilu,
                                                             out, outBS, outPitch, toMask, shift, bboxes, batch0); break;
    }
}

extern "C" void kernel_launch(void* const* d_in, const int* in_sizes, int n_in,
                              void* d_out, int out_size, void* d_ws, size_t ws_size,
                              hipStream_t stream)
{
    const float* x  = (const float*)d_in[0];
    const float* em[4];
    const float* gw[4];
    const float* gb[4];
    const float* cw[4];
    const float* cb[4];
    for (int j = 0; j < 4; j++) {
        em[j] = (const float*)d_in[1 + j];
        gw[j] = (const float*)d_in[5 + 4 * j];
        gb[j] = (const float*)d_in[6 + 4 * j];
        cw[j] = (const float*)d_in[7 + 4 * j];
        cb[j] = (const float*)d_in[8 + 4 * j];
    }
    const int* bboxes = (const int*)d_in[21];
    float* out = (float*)d_out;
    float* ws  = (float*)d_ws;

    const int chans[4] = {256, 64, 16, 4};
    const int couts[4] = {64, 16, 4, 1};

    const long long A_OFF  = 256;
    const long long A_SLOT = 1048576;   // floats: co_j * (128<<j)^2, same all stages
    const long long B_SLOT = 4194304;   // floats: c_j * (128<<j)^2, same all stages

    bool par = ws_size >= (size_t)(A_OFF + 4 * A_SLOT + 4 * B_SLOT) * 4;
    int nA = par ? 4 : 1;
    float* accs = ws;
    float* bufA = ws + A_OFF;
    float* bufB = ws + A_OFF + nA * A_SLOT;

    // mask = -100 everywhere
    fill_kernel<<<(4194304 + 255) / 256, 256, 0, stream>>>(out, 4194304, -100.0f);

    if (par) {
        for (int j = 0; j < 4; j++) {
            int c = chans[j], co = couts[j], shift = j;
            int inPitch = 64 << j;
            long long inPlane = (long long)inPitch * inPitch;
            int upPitch = 128 << j;
            int tiles = upPitch / 16;
            int E = 128 << j;
            long long emStride = (long long)c * E * E;

            const float* gin = (j == 0) ? x : bufA;
            long long ginStride = (j == 0) ? (long long)256 * 64 * 64 : A_SLOT;
            int useOrig = (j == 0) ? 1 : 0;

            zero8_kernel<<<1, 64, 0, stream>>>(accs);
            gn_reduce_kernel<<<dim3(512, 1, 4), 256, 0, stream>>>(
                gin, ginStride, inPitch, inPlane, useOrig, c, shift, bboxes, 0, accs);
            normup_kernel<<<dim3(tiles, tiles * c, 4), dim3(16, 16), 0, stream>>>(
                gin, ginStride, inPitch, inPlane, useOrig,
                em[j], emStride, E, gw[j], gb[j], accs,
                bufB, B_SLOT, upPitch, c, shift, bboxes, 0, tiles);
            launch_conv(co, dim3(tiles, tiles, 4),
                        bufB, B_SLOT, upPitch, cw[j], cb[j], c, (j < 3) ? 1 : 0,
                        (j < 3) ? bufA : out, (j < 3) ? A_SLOT : 0, upPitch,
                        (j == 3) ? 1 : 0, shift, bboxes, 0, stream);
        }
    } else {
        for (int i = 0; i < 4; i++) {
            for (int j = 0; j < 4; j++) {
                int c = chans[j], co = couts[j], shift = j;
                int inPitch = 64 << j;
                long long inPlane = (long long)inPitch * inPitch;
                int upPitch = 128 << j;
                int tiles = upPitch / 16;
                int E = 128 << j;
                long long emStride = (long long)c * E * E;

                const float* gin = (j == 0) ? (x + (long long)i * 256 * 64 * 64) : bufA;
                int useOrig = (j == 0) ? 1 : 0;

                zero8_kernel<<<1, 64, 0, stream>>>(accs);
                gn_reduce_kernel<<<dim3(512, 1, 1), 256, 0, stream>>>(
                    gin, 0, inPitch, inPlane, useOrig, c, shift, bboxes, i, accs);
                normup_kernel<<<dim3(tiles, tiles * c, 1), dim3(16, 16), 0, stream>>>(
                    gin, 0, inPitch, inPlane, useOrig,
                    em[j] + (long long)i * emStride, 0, E, gw[j], gb[j], accs,
                    bufB, 0, upPitch, c, shift, bboxes, i, tiles);
                launch_conv(co, dim3(tiles, tiles, 1),
                            bufB, 0, upPitch, cw[j], cb[j], c, (j < 3) ? 1 : 0,
                            (j < 3) ? bufA : out, 0, upPitch,
                            (j == 3) ? 1 : 0, shift, bboxes, i, stream);
            }
        }
    }
}

// Round 3
// 3151.493 us; speedup vs baseline: 2.3500x; 2.3500x over previous
//
#include <hip/hip_runtime.h>

#define EPS 1e-5f

// ---------------------------------------------------------------------------
// fill output mask with -100
// ---------------------------------------------------------------------------
__global__ void fill_kernel(float* __restrict__ out, int n, float v) {
    int i = blockIdx.x * blockDim.x + threadIdx.x;
    if (i < n) out[i] = v;
}

__global__ void zero8_kernel(float* __restrict__ a) {
    if (threadIdx.x < 8) a[threadIdx.x] = 0.f;
}

// ---------------------------------------------------------------------------
// GroupNorm(1) reduction: sum & sumsq over the (c, h, w) crop -> accs[2*batch]
// ---------------------------------------------------------------------------
__global__ void gn_reduce_kernel(const float* __restrict__ in, long long inBatchStride,
                                 int inPitch, long long inPlane, int useOrig,
                                 int c, int shift, const int* __restrict__ bboxes,
                                 int batch0, float* __restrict__ accs)
{
    int batch = batch0 + blockIdx.z;
    const int* bb = bboxes + 4 * batch;
    int l = bb[0], t = bb[1], r = bb[2], btm = bb[3];
    int h = (btm - t) << shift;
    int w = (r   - l) << shift;
    int oy = useOrig ? t : 0;   // only used at stage 0 (shift==0)
    int ox = useOrig ? l : 0;
    int count = c * h * w;
    const float* base = in + (long long)blockIdx.z * inBatchStride;

    float s = 0.f, s2 = 0.f;
    int stride = gridDim.x * blockDim.x;
    for (int idx = blockIdx.x * blockDim.x + threadIdx.x; idx < count; idx += stride) {
        int xw   = idx % w;
        int rest = idx / w;
        int y    = rest % h;
        int ch   = rest / h;
        float v = base[(long long)ch * inPlane + (long long)(y + oy) * inPitch + (xw + ox)];
        s  += v;
        s2 += v * v;
    }
    // wave64 reduction
    for (int off = 32; off > 0; off >>= 1) {
        s  += __shfl_down(s, off);
        s2 += __shfl_down(s2, off);
    }
    if ((threadIdx.x & 63) == 0) {
        atomicAdd(&accs[2 * batch],     s);
        atomicAdd(&accs[2 * batch + 1], s2);
    }
}

// ---------------------------------------------------------------------------
// normalize (affine folded) + bicubic 2x (both axes, 16 taps) + add em crop
// writes bufB (c, 2h, 2w) with pitch outPitch
// ---------------------------------------------------------------------------
__global__ void normup_kernel(const float* __restrict__ in, long long inBatchStride,
                              int inPitch, long long inPlane, int useOrig,
                              const float* __restrict__ em, long long emBatchStride, int emPitch,
                              const float* __restrict__ gw, const float* __restrict__ gb,
                              const float* __restrict__ accs,
                              float* __restrict__ outB, long long outBatchStride, int outPitch,
                              int c, int shift, const int* __restrict__ bboxes,
                              int batch0, int tilesY)
{
    int batch = batch0 + blockIdx.z;
    const int* bb = bboxes + 4 * batch;
    int l = bb[0], t = bb[1], r = bb[2], btm = bb[3];
    int h = (btm - t) << shift;
    int w = (r   - l) << shift;
    int H2 = 2 * h, W2 = 2 * w;

    int ch = blockIdx.y / tilesY;
    int ty = blockIdx.y % tilesY;
    int y2 = ty * 16 + threadIdx.y;
    int x2 = blockIdx.x * 16 + threadIdx.x;
    if (y2 >= H2 || x2 >= W2) return;

    float count = (float)(c * h * w);
    float m  = accs[2 * batch] / count;
    float var = accs[2 * batch + 1] / count - m * m;
    float rs = rsqrtf(fmaxf(var, 0.f) + EPS);
    float alpha = rs * gw[ch];
    float beta  = gb[ch] - m * alpha;

    int oy = useOrig ? t : 0;
    int ox = useOrig ? l : 0;
    const float* base = in + (long long)blockIdx.z * inBatchStride + (long long)ch * inPlane;

    const float Wv[2][4] = {
        {-0.03515625f, 0.26171875f, 0.87890625f, -0.10546875f},   // even (W75)
        {-0.10546875f, 0.87890625f, 0.26171875f, -0.03515625f}};  // odd  (W25)

    int iy = y2 >> 1, py = y2 & 1;
    int ix = x2 >> 1, px = x2 & 1;
    int by = iy - 2 + py;
    int bx = ix - 2 + px;

    float acc = 0.f;
    #pragma unroll
    for (int a = 0; a < 4; a++) {
        int ry = by + a;
        ry = ry < 0 ? 0 : (ry > h - 1 ? h - 1 : ry);
        const float* rowp = base + (long long)(ry + oy) * inPitch + ox;
        float rsum = 0.f;
        #pragma unroll
        for (int q = 0; q < 4; q++) {
            int rx = bx + q;
            rx = rx < 0 ? 0 : (rx > w - 1 ? w - 1 : rx);
            rsum += Wv[px][q] * rowp[rx];
        }
        acc += Wv[py][a] * rsum;
    }

    float val = alpha * acc + beta;
    int S = 2 << shift;  // 2^(j+1)
    val += em[(long long)blockIdx.z * emBatchStride + (long long)ch * emPitch * emPitch
              + (long long)(t * S + y2) * emPitch + (l * S + x2)];

    outB[(long long)blockIdx.z * outBatchStride + (long long)ch * outPitch * outPitch
         + (long long)y2 * outPitch + x2] = val;
}

// ---------------------------------------------------------------------------
// conv3x3 (zero pad) + bias (+ silu), COT output channels per thread.
// Block = 16x16 spatial tile; oc-group from blockIdx.y; input tile staged in
// LDS in chunks of CICH planes; weights are block-uniform -> scalar loads.
// ---------------------------------------------------------------------------
#define CICH 4

template<int COT>
__global__ void __launch_bounds__(256)
conv_reg_kernel(const float* __restrict__ inB, long long inBatchStride, int inPitch,
                const float* __restrict__ wts, const float* __restrict__ bias,
                int cin, int doSilu,
                float* __restrict__ out, long long outBatchStride, int outPitch,
                int toMask, int shift, const int* __restrict__ bboxes,
                int batch0, int tilesY)
{
    int batch = batch0 + blockIdx.z;
    const int* bb = bboxes + 4 * batch;
    int l = bb[0], t = bb[1], r = bb[2], btm = bb[3];
    int h = (btm - t) << shift;
    int w = (r   - l) << shift;
    int H2 = 2 * h, W2 = 2 * w;

    int og = blockIdx.y / tilesY;
    int ty = blockIdx.y % tilesY;
    int oc0 = og * COT;
    int y0 = ty * 16;
    int x0 = blockIdx.x * 16;
    if (y0 >= H2 || x0 >= W2) return;  // uniform over block

    int ly = threadIdx.y, lx = threadIdx.x;
    int oy2 = y0 + ly, ox2 = x0 + lx;
    bool act = (oy2 < H2) && (ox2 < W2);
    int tid = ly * 16 + lx;

    // padded row stride 20 to break bank-conflict strides
    __shared__ float tile[CICH][18][20];

    const float* base = inB + (long long)blockIdx.z * inBatchStride;
    long long plane = (long long)inPitch * inPitch;

    float acc[COT];
    #pragma unroll
    for (int o = 0; o < COT; o++) acc[o] = 0.f;

    long long ocStride = (long long)cin * 9;

    for (int ci0 = 0; ci0 < cin; ci0 += CICH) {
        // stage CICH input planes (18x18 halo tile each) into LDS
        for (int q = tid; q < CICH * 324; q += 256) {
            int p   = q / 324;
            int rem = q - p * 324;
            int yy  = rem / 18;
            int xx  = rem - yy * 18;
            int gy = y0 - 1 + yy, gx = x0 - 1 + xx;
            float v = (gy >= 0 && gy < H2 && gx >= 0 && gx < W2)
                          ? base[(long long)(ci0 + p) * plane + (long long)gy * inPitch + gx]
                          : 0.f;
            tile[p][yy][xx] = v;
        }
        __syncthreads();

        #pragma unroll
        for (int p = 0; p < CICH; p++) {
            int ci = ci0 + p;
            float v00 = tile[p][ly    ][lx], v01 = tile[p][ly    ][lx + 1], v02 = tile[p][ly    ][lx + 2];
            float v10 = tile[p][ly + 1][lx], v11 = tile[p][ly + 1][lx + 1], v12 = tile[p][ly + 1][lx + 2];
            float v20 = tile[p][ly + 2][lx], v21 = tile[p][ly + 2][lx + 1], v22 = tile[p][ly + 2][lx + 2];

            const float* wbase = wts + ((long long)oc0 * cin + (long long)ci) * 9;
            #pragma unroll
            for (int o = 0; o < COT; o++) {
                const float* wp = wbase + (long long)o * ocStride;  // block-uniform -> s_load
                acc[o] += wp[0] * v00 + wp[1] * v01 + wp[2] * v02
                        + wp[3] * v10 + wp[4] * v11 + wp[5] * v12
                        + wp[6] * v20 + wp[7] * v21 + wp[8] * v22;
            }
        }
        __syncthreads();
    }

    if (!act) return;

    #pragma unroll
    for (int o = 0; o < COT; o++) {
        float v = acc[o] + bias[oc0 + o];
        if (doSilu) v = v / (1.f + __expf(-v));
        if (toMask) {
            int S = 2 << shift;   // 16 at stage 3
            out[(long long)batch * 1024 * 1024 + (long long)(t * S + oy2) * 1024 + (l * S + ox2)] = v;
        } else {
            out[(long long)blockIdx.z * outBatchStride + (long long)(oc0 + o) * outPitch * outPitch
                + (long long)oy2 * outPitch + ox2] = v;
        }
    }
}

// ---------------------------------------------------------------------------
static inline void launch_conv(int co, int tiles, int nz, const float* inB, long long inBS, int inPitch,
                               const float* wts, const float* bias, int cin, int doSilu,
                               float* out, long long outBS, int outPitch,
                               int toMask, int shift, const int* bboxes, int batch0,
                               hipStream_t stream)
{
    dim3 blk(16, 16);
    if (co == 64) {       // 4 groups of 16
        conv_reg_kernel<16><<<dim3(tiles, tiles * 4, nz), blk, 0, stream>>>(
            inB, inBS, inPitch, wts, bias, cin, doSilu, out, outBS, outPitch,
            toMask, shift, bboxes, batch0, tiles);
    } else if (co == 16) {
        conv_reg_kernel<16><<<dim3(tiles, tiles, nz), blk, 0, stream>>>(
            inB, inBS, inPitch, wts, bias, cin, doSilu, out, outBS, outPitch,
            toMask, shift, bboxes, batch0, tiles);
    } else if (co == 4) {
        conv_reg_kernel<4><<<dim3(tiles, tiles, nz), blk, 0, stream>>>(
            inB, inBS, inPitch, wts, bias, cin, doSilu, out, outBS, outPitch,
            toMask, shift, bboxes, batch0, tiles);
    } else {
        conv_reg_kernel<1><<<dim3(tiles, tiles, nz), blk, 0, stream>>>(
            inB, inBS, inPitch, wts, bias, cin, doSilu, out, outBS, outPitch,
            toMask, shift, bboxes, batch0, tiles);
    }
}

extern "C" void kernel_launch(void* const* d_in, const int* in_sizes, int n_in,
                              void* d_out, int out_size, void* d_ws, size_t ws_size,
                              hipStream_t stream)
{
    const float* x  = (const float*)d_in[0];
    const float* em[4];
    const float* gw[4];
    const float* gb[4];
    const float* cw[4];
    const float* cb[4];
    for (int j = 0; j < 4; j++) {
        em[j] = (const float*)d_in[1 + j];
        gw[j] = (const float*)d_in[5 + 4 * j];
        gb[j] = (const float*)d_in[6 + 4 * j];
        cw[j] = (const float*)d_in[7 + 4 * j];
        cb[j] = (const float*)d_in[8 + 4 * j];
    }
    const int* bboxes = (const int*)d_in[21];
    float* out = (float*)d_out;
    float* ws  = (float*)d_ws;

    const int chans[4] = {256, 64, 16, 4};
    const int couts[4] = {64, 16, 4, 1};

    const long long A_OFF  = 256;
    const long long A_SLOT = 1048576;   // floats
    const long long B_SLOT = 4194304;   // floats: c_j * (128<<j)^2, same all stages

    bool par = ws_size >= (size_t)(A_OFF + 4 * A_SLOT + 4 * B_SLOT) * 4;
    int nA = par ? 4 : 1;
    float* accs = ws;
    float* bufA = ws + A_OFF;
    float* bufB = ws + A_OFF + nA * A_SLOT;

    // mask = -100 everywhere
    fill_kernel<<<(4194304 + 255) / 256, 256, 0, stream>>>(out, 4194304, -100.0f);

    if (par) {
        for (int j = 0; j < 4; j++) {
            int c = chans[j], co = couts[j], shift = j;
            int inPitch = 64 << j;
            long long inPlane = (long long)inPitch * inPitch;
            int upPitch = 128 << j;
            int tiles = upPitch / 16;
            int E = 128 << j;
            long long emStride = (long long)c * E * E;

            const float* gin = (j == 0) ? x : bufA;
            long long ginStride = (j == 0) ? (long long)256 * 64 * 64 : A_SLOT;
            int useOrig = (j == 0) ? 1 : 0;

            zero8_kernel<<<1, 64, 0, stream>>>(accs);
            gn_reduce_kernel<<<dim3(512, 1, 4), 256, 0, stream>>>(
                gin, ginStride, inPitch, inPlane, useOrig, c, shift, bboxes, 0, accs);
            normup_kernel<<<dim3(tiles, tiles * c, 4), dim3(16, 16), 0, stream>>>(
                gin, ginStride, inPitch, inPlane, useOrig,
                em[j], emStride, E, gw[j], gb[j], accs,
                bufB, B_SLOT, upPitch, c, shift, bboxes, 0, tiles);
            launch_conv(co, tiles, 4,
                        bufB, B_SLOT, upPitch, cw[j], cb[j], c, (j < 3) ? 1 : 0,
                        (j < 3) ? bufA : out, (j < 3) ? A_SLOT : 0, upPitch,
                        (j == 3) ? 1 : 0, shift, bboxes, 0, stream);
        }
    } else {
        for (int i = 0; i < 4; i++) {
            for (int j = 0; j < 4; j++) {
                int c = chans[j], co = couts[j], shift = j;
                int inPitch = 64 << j;
                long long inPlane = (long long)inPitch * inPitch;
                int upPitch = 128 << j;
                int tiles = upPitch / 16;
                int E = 128 << j;
                long long emStride = (long long)c * E * E;

                const float* gin = (j == 0) ? (x + (long long)i * 256 * 64 * 64) : bufA;
                int useOrig = (j == 0) ? 1 : 0;

                zero8_kernel<<<1, 64, 0, stream>>>(accs);
                gn_reduce_kernel<<<dim3(512, 1, 1), 256, 0, stream>>>(
                    gin, 0, inPitch, inPlane, useOrig, c, shift, bboxes, i, accs);
                normup_kernel<<<dim3(tiles, tiles * c, 1), dim3(16, 16), 0, stream>>>(
                    gin, 0, inPitch, inPlane, useOrig,
                    em[j] + (long long)i * emStride, 0, E, gw[j], gb[j], accs,
                    bufB, 0, upPitch, c, shift, bboxes, i, tiles);
                launch_conv(co, tiles, 1,
                            bufB, 0, upPitch, cw[j], cb[j], c, (j < 3) ? 1 : 0,
                            (j < 3) ? bufA : out, 0, upPitch,
                            (j == 3) ? 1 : 0, shift, bboxes, i, stream);
            }
        }
    }
}